// Round 4
// baseline (387.598 us; speedup 1.0000x reference)
//
#include <hip/hip_runtime.h>
#include <hip/hip_bf16.h>
#include <stdint.h>

// out = ReLU((din*mask + bias*mask) @ W). din [8192,4096] fp32 ~10% dense,
// W [4096,4096] fp32 row-major (K = rows), bias [4096].
// R7: prep_a (16 elems/thread) + transpose_w (64x64 LDS tile) -- kept verbatim.
// R8: GEMM restructured to the 256^2 8-wave counted-vmcnt pipeline (T3+T4+T5):
//   - BM=BN=256, BK=128, 512 threads (2M x 4N waves), per-wave 128x64 output.
//   - LDS 128 KB: 2 slots x (A 32KB + B 32KB), double-buffered over K-tiles.
//   - Schedule per K-tile t (slot s=t&1):
//       vmcnt(8); s_barrier;            // tile t's 8 loads (mine) landed ->
//                                       // after barrier, everyone's landed
//       ds_read kstep0; MFMA kstep0;    // setprio(1) around MFMA
//       ds_read kstep1;
//       lgkmcnt(0); sched_barrier; s_barrier;  // slot s fully read by ALL waves
//       stage tile t+2 -> slot s;       // 8 global_load_lds, issue-only
//       MFMA kstep1;                    // hides load issue + HBM latency
//     vmcnt NEVER drains to 0 in the main loop (T4); raw s_barrier (not
//     __syncthreads) avoids the compiler's vmcnt(0) barrier drain.
//   - Invariant (whole-tile granularity): at iter t's wait, outstanding
//     vmem = tile t's 8 + tile t+1's 8; vmcnt(8) retires exactly tile t.
//     Final iter peeled with vmcnt(0). Restage of slot s only after
//     lgkmcnt(0)+barrier proves all waves' ds_reads of slot s completed.
//   - XOR swizzle (T2) identical to R4: chunk c of 128B row r stored at
//     position c^(r&7); realized by permuting per-lane global chunk.
//   - Bijective XCD swizzle on 512 blocks (512%8==0).
//   Quantization math & K accumulation order unchanged => absmax 1.5.

#define M_ROWS 8192
#define N_COLS 4096
#define K_DIM  4096

#define BM 256
#define BN 256
#define BK 128              // i8 elements per K-tile (128 bytes per row)
#define NT (K_DIM / BK)     // 32 K-tiles

typedef int int32x4_t __attribute__((ext_vector_type(4)));

#define SA (8.0f / 127.0f)
#define SW (1.0f / 127.0f)
#define INV_SA (127.0f / 8.0f)
#define INV_SW 127.0f
#define DEQ (SA * SW)

__device__ __forceinline__ void gload_lds16(const void* gsrc, void* ldst) {
  // 16B per lane, LDS dest = wave-uniform base + lane*16 (hardware rule).
  __builtin_amdgcn_global_load_lds(
      (const __attribute__((address_space(1))) uint32_t*)gsrc,
      (__attribute__((address_space(3))) uint32_t*)ldst,
      16, 0, 0);
}

__device__ __forceinline__ int quant_i8(float x, float inv_s) {
  float q = fminf(fmaxf(x * inv_s, -127.f), 127.f);
  return (int)lrintf(q);
}

// A_i8[b,j] = q(din != 0 ? din + bias[j] : 0); 16 elems/thread, one int4 store.
__global__ __launch_bounds__(256)
void prep_a(const float* __restrict__ din, const float* __restrict__ bias,
            int32x4_t* __restrict__ Ai8) {
  const int64_t t16 = (int64_t)blockIdx.x * 256 + threadIdx.x;  // 16-elem group
  const int64_t e0 = t16 * 16;
  const int j0 = (int)(e0 & (K_DIM - 1));
  const float4* dp = (const float4*)(din + e0);
  const float4* bp = (const float4*)(bias + j0);
  int out[4];
#pragma unroll
  for (int c = 0; c < 4; ++c) {
    float4 d = dp[c];
    float4 bv = bp[c];
    int q0 = quant_i8(d.x != 0.f ? d.x + bv.x : 0.f, INV_SA);
    int q1 = quant_i8(d.y != 0.f ? d.y + bv.y : 0.f, INV_SA);
    int q2 = quant_i8(d.z != 0.f ? d.z + bv.z : 0.f, INV_SA);
    int q3 = quant_i8(d.w != 0.f ? d.w + bv.w : 0.f, INV_SA);
    out[c] = (q0 & 0xff) | ((q1 & 0xff) << 8) | ((q2 & 0xff) << 16) | ((q3 & 0xff) << 24);
  }
  Ai8[t16] = (int32x4_t){out[0], out[1], out[2], out[3]};
}

// Wt_i8[n,j] = q(W[j,n]) via 64x64 LDS tile; 16B contiguous int4 writes.
__global__ __launch_bounds__(256)
void transpose_w(const float* __restrict__ W, char* __restrict__ Wt) {
  __shared__ __align__(16) float tile[64][68];
  const int tid = threadIdx.x;
  const int n0 = blockIdx.x * 64;
  const int j0 = blockIdx.y * 64;
#pragma unroll
  for (int c = 0; c < 4; ++c) {
    const int idx = c * 256 + tid;
    const int r = idx >> 4;
    const int q = idx & 15;
    float4 v = *(const float4*)(W + (int64_t)(j0 + r) * K_DIM + (n0 + q * 4));
    *(float4*)&tile[r][q * 4] = v;
  }
  __syncthreads();
  const int n = tid >> 2;
  const int jc = (tid & 3) * 16;
  int w[4];
#pragma unroll
  for (int d = 0; d < 4; ++d) {
    int q0 = quant_i8(tile[jc + d * 4 + 0][n], INV_SW);
    int q1 = quant_i8(tile[jc + d * 4 + 1][n], INV_SW);
    int q2 = quant_i8(tile[jc + d * 4 + 2][n], INV_SW);
    int q3 = quant_i8(tile[jc + d * 4 + 3][n], INV_SW);
    w[d] = (q0 & 0xff) | ((q1 & 0xff) << 8) | ((q2 & 0xff) << 16) | ((q3 & 0xff) << 24);
  }
  *(int32x4_t*)(Wt + (int64_t)(n0 + n) * K_DIM + j0 + jc) =
      (int32x4_t){w[0], w[1], w[2], w[3]};
}

// C[M,N] = relu(A[M,K] * Bt[N,K]^T) * DEQ, i8 in / fp32 out.
__global__ __launch_bounds__(512, 2)
void gemm_i8_relu(const char* __restrict__ A, const char* __restrict__ Bt,
                  float* __restrict__ C) {
  // [slot 0: A 32K | B 32K][slot 1: A 32K | B 32K]
  __shared__ __align__(16) char lds[131072];

  const int tid = threadIdx.x;   // 0..511
  const int wave = tid >> 6;     // 0..7
  const int lane = tid & 63;
  const int wm = wave >> 2;      // 0..1  (M-wave)
  const int wn = wave & 3;       // 0..3  (N-wave)
  const int quad = lane >> 4;
  const int l16 = lane & 15;
  const int r7 = l16 & 7;        // row&7 of every fragment row (bases mult. of 16)

  // Bijective XCD swizzle: 512 blocks = 8 XCDs x 64 contiguous.
  const int lin = blockIdx.y * 16 + blockIdx.x;
  const int lin2 = (lin & 7) * 64 + (lin >> 3);
  const int bm = lin2 >> 4;      // 0..31
  const int bn = lin2 & 15;      // 0..15

  // Staging: per tile, A = 32KB = 32 ops of 1KB (64 lanes x 16B); op o covers
  // rows [o*8, o*8+8). Each wave issues ops o = wave*4+i for A and B (8 vmem
  // ops per tile per wave -- the unit of the vmcnt(8) invariant). Swizzle:
  // lane fetches global chunk (l%8)^(l/8) of its 128B row -> slot (row, pos p)
  // holds chunk p^(row&7). Same global 128B segment => coalescing unchanged.
  const int lrow8 = lane >> 3;
  const int lchunk = lane & 7;
  const int swz = lchunk ^ lrow8;

  const char* aCur[4];
  const char* bCur[4];
  char* aDst[4];
  char* bDst[4];
#pragma unroll
  for (int i = 0; i < 4; ++i) {
    const int o = wave * 4 + i;  // 0..31
    aCur[i] = A + (int64_t)(bm * BM + o * 8 + lrow8) * K_DIM + swz * 16;
    bCur[i] = Bt + (int64_t)(bn * BN + o * 8 + lrow8) * K_DIM + swz * 16;
    aDst[i] = lds + o * 1024 + lane * 16;          // + slot*65536
    bDst[i] = lds + 32768 + o * 1024 + lane * 16;  // + slot*65536
  }

  // stage current tile into slot, advance global pointers by BK.
  auto stage = [&](int slot) {
    const int so = slot * 65536;
#pragma unroll
    for (int i = 0; i < 4; ++i) {
      gload_lds16(aCur[i], aDst[i] + so);
      gload_lds16(bCur[i], bDst[i] + so);
      aCur[i] += BK;
      bCur[i] += BK;
    }
  };

  int32x4_t acc[8][4];
#pragma unroll
  for (int mf = 0; mf < 8; ++mf)
#pragma unroll
    for (int nf = 0; nf < 4; ++nf)
      acc[mf][nf] = (int32x4_t){0, 0, 0, 0};

  int32x4_t af[8], bf[4];
  // kstep ks: lane (l16,quad) needs chunk kc = ks*4+quad of its row, stored at
  // position kc^(r&7). Wave wm reads A rows wm*128+mf*16+l16; wn reads B rows
  // wn*64+nf*16+l16.
  auto load_frags = [&](int slot, int ks) {
    const int pos = (((ks << 2) + quad) ^ r7) * 16;
    const char* Ab = lds + slot * 65536 + (wm * 128 + l16) * BK + pos;
    const char* Bb = lds + slot * 65536 + 32768 + (wn * 64 + l16) * BK + pos;
#pragma unroll
    for (int mf = 0; mf < 8; ++mf)
      af[mf] = *(const int32x4_t*)(Ab + mf * 16 * BK);
#pragma unroll
    for (int nf = 0; nf < 4; ++nf)
      bf[nf] = *(const int32x4_t*)(Bb + nf * 16 * BK);
  };

  auto do_mfma = [&]() {
    __builtin_amdgcn_s_setprio(1);
#pragma unroll
    for (int mf = 0; mf < 8; ++mf)
#pragma unroll
      for (int nf = 0; nf < 4; ++nf)
        acc[mf][nf] = __builtin_amdgcn_mfma_i32_16x16x64_i8(af[mf], bf[nf],
                                                            acc[mf][nf], 0, 0, 0);
    __builtin_amdgcn_s_setprio(0);
  };

  // Prologue: stage tiles 0 and 1 (16 vmem ops outstanding).
  stage(0);
  stage(1);

  // Main loop: iters t = 0..NT-2. At iter t's wait, outstanding = tile t (8)
  // + tile t+1 (8); vmcnt(8) retires exactly tile t (oldest-first semantics).
  for (int t = 0; t < NT - 1; ++t) {
    const int s = t & 1;
    asm volatile("s_waitcnt vmcnt(8)" ::: "memory");
    __builtin_amdgcn_s_barrier();

    load_frags(s, 0);
    do_mfma();
    load_frags(s, 1);

    // All my ds_reads of slot s done; barrier makes it true for every wave.
    asm volatile("s_waitcnt lgkmcnt(0)" ::: "memory");
    __builtin_amdgcn_sched_barrier(0);
    __builtin_amdgcn_s_barrier();

    if (t + 2 < NT) stage(s);  // overwrite freed slot with tile t+2 (issue-only)

    do_mfma();  // kstep1 on registers; hides load issue + HBM latency
  }

  // Final iter t = NT-1 (slot 1): only tile NT-1's 8 loads outstanding.
  asm volatile("s_waitcnt vmcnt(0)" ::: "memory");
  __builtin_amdgcn_s_barrier();
  load_frags(1, 0);
  do_mfma();
  load_frags(1, 1);
  do_mfma();

  // Epilogue: C/D layout col=lane&15, row=quad*4+reg (dtype-independent).
#pragma unroll
  for (int mf = 0; mf < 8; ++mf) {
#pragma unroll
    for (int nf = 0; nf < 4; ++nf) {
      const int col = bn * BN + wn * 64 + nf * 16 + l16;
      const int row0 = bm * BM + wm * 128 + mf * 16 + quad * 4;
#pragma unroll
      for (int i = 0; i < 4; ++i) {
        int vi = acc[mf][nf][i];
        float v = (float)(vi > 0 ? vi : 0) * DEQ;
        C[(int64_t)(row0 + i) * N_COLS + col] = v;
      }
    }
  }
}

extern "C" void kernel_launch(void* const* d_in, const int* in_sizes, int n_in,
                              void* d_out, int out_size, void* d_ws, size_t ws_size,
                              hipStream_t stream) {
  const float* din = (const float*)d_in[0];     // [8192, 4096] fp32
  const float* weight = (const float*)d_in[1];  // [4096, 4096] fp32
  const float* bias = (const float*)d_in[2];    // [4096] fp32
  float* out = (float*)d_out;                   // [8192, 4096] fp32

  int32x4_t* Ai8 = (int32x4_t*)d_ws;                           // 33.6 MB
  char* Wt = (char*)d_ws + (size_t)M_ROWS * K_DIM;             // +16.8 MB

  prep_a<<<M_ROWS * K_DIM / 4096, 256, 0, stream>>>(din, bias, Ai8);
  transpose_w<<<dim3(N_COLS / 64, K_DIM / 64), 256, 0, stream>>>(weight, (char*)Wt);
  gemm_i8_relu<<<dim3(N_COLS / BN, M_ROWS / BM), 512, 0, stream>>>(
      (const char*)Ai8, (const char*)Wt, out);
}